// Round 1
// baseline (111.305 us; speedup 1.0000x reference)
//
#include <hip/hip_runtime.h>
#include <hip/hip_bf16.h>

typedef __attribute__((ext_vector_type(8))) short short8;
typedef __attribute__((ext_vector_type(4))) float f32x4;

#define L 1024
#define D 1024
#define NHEADS 16
#define DK 64
#define NB 4

static __device__ __forceinline__ unsigned short f2bf(float f) {
  union { float f; unsigned int u; } c; c.f = f;
  unsigned int u = c.u;
  u += 0x7fffu + ((u >> 16) & 1u);   // round-to-nearest-even
  return (unsigned short)(u >> 16);
}

static __device__ __forceinline__ void gload_lds16(const void* gsrc, void* ldst) {
  __builtin_amdgcn_global_load_lds(
      (const __attribute__((address_space(1))) void*)gsrc,
      (__attribute__((address_space(3))) void*)ldst, 16, 0, 0);
}

// ---------------- kernel 1: cast Wq|Wk -> bf16 (stacked [2048][1024]) -------
__global__ __launch_bounds__(256) void cast_w_kernel(const float* __restrict__ Wq,
                                                     const float* __restrict__ Wk,
                                                     unsigned short* __restrict__ w) {
  int idx = blockIdx.x * 256 + threadIdx.x;           // 524288 float4's
  const float* src = (idx < 262144) ? Wq : Wk;
  int rel = (idx < 262144) ? idx : idx - 262144;
  float4 v = ((const float4*)src)[rel];
  ushort4 o;
  o.x = f2bf(v.x); o.y = f2bf(v.y); o.z = f2bf(v.z); o.w = f2bf(v.w);
  ((ushort4*)w)[idx] = o;
}

// ---------------- kernel 2: gather + LayerNorm -> xn bf16 [4096][1024] ------
__global__ __launch_bounds__(256) void ln_gather_kernel(const int* __restrict__ leaf,
                                                        const float* __restrict__ p_emb,
                                                        const float* __restrict__ g,
                                                        const float* __restrict__ bcoef,
                                                        unsigned short* __restrict__ xn) {
  int row = blockIdx.x;          // 0..4095
  int t = threadIdx.x;           // 0..255
  int lane = t & 63, w = t >> 6;
  int leafv = leaf[row];
  float4 xv = ((const float4*)(p_emb + (size_t)leafv * D))[t];
  float s  = xv.x + xv.y + xv.z + xv.w;
  float s2 = xv.x*xv.x + xv.y*xv.y + xv.z*xv.z + xv.w*xv.w;
  #pragma unroll
  for (int o = 1; o < 64; o <<= 1) {
    s  += __shfl_xor(s, o);
    s2 += __shfl_xor(s2, o);
  }
  __shared__ float red[8];
  if (lane == 0) { red[w*2] = s; red[w*2+1] = s2; }
  __syncthreads();
  float st  = red[0] + red[2] + red[4] + red[6];
  float s2t = red[1] + red[3] + red[5] + red[7];
  float mu = st * (1.0f/1024.0f);
  float var = s2t * (1.0f/1024.0f) - mu*mu;
  float rs = rsqrtf(var + 1e-5f);
  float4 gv = ((const float4*)g)[t];
  float4 bv = ((const float4*)bcoef)[t];
  ushort4 o;
  o.x = f2bf((xv.x - mu) * rs * gv.x + bv.x);
  o.y = f2bf((xv.y - mu) * rs * gv.y + bv.y);
  o.z = f2bf((xv.z - mu) * rs * gv.z + bv.z);
  o.w = f2bf((xv.w - mu) * rs * gv.w + bv.w);
  ((ushort4*)xn)[row * 256 + t] = o;
}

// ---------------- kernel 3: T5 bucket precompute, u8 [4][1024][1024] --------
__global__ __launch_bounds__(256) void bucket_kernel(const int* __restrict__ leaf,
                                                     unsigned char* __restrict__ bucket) {
  int idx = blockIdx.x * 256 + threadIdx.x;           // 4M
  int j = idx & 1023;
  int rest = idx >> 10;
  int i = rest & 1023;
  int b = rest >> 10;
  int li = leaf[b * L + i];
  int lj = leaf[b * L + j];
  int n = li - lj;                 // n = -(rel) = leaf[i]-leaf[j]
  int ret = 0;
  if (n < 0) { ret = 16; n = -n; }
  int val;
  if (n < 8) {
    val = n;
  } else {
    val = 8 + (int)(logf((float)n * 0.125f) * 2.8853900817779268f);
    if (val > 15) val = 15;
  }
  val += ret;
  if (li == 0 || lj == 0) val = 32;
  bucket[idx] = (unsigned char)val;
}

// ---------------- kernel 4: fused q/k GEMM (NT, bf16 MFMA) ------------------
// C[m,n] = sum_d xn[m,d]*W'[n,d]; n<1024 -> q (scale 1/8, bias bq), else k.
// Output written in MFMA-fragment-native layout:
//   ws[bh][i>>4][k>>3][i&15][k&7]   (per bh: 64*8*16*8 = 65536 bf16)
__global__ __launch_bounds__(256) void qk_gemm_kernel(const unsigned short* __restrict__ xn,
                                                      const unsigned short* __restrict__ wqk,
                                                      const float* __restrict__ bq,
                                                      const float* __restrict__ bk,
                                                      unsigned short* __restrict__ qws,
                                                      unsigned short* __restrict__ kws) {
  __shared__ __align__(16) unsigned short As[2][128 * 32];
  __shared__ __align__(16) unsigned short Bs[2][128 * 32];
  int t = threadIdx.x;
  int lane = t & 63, w = t >> 6;
  int wr = w >> 1, wc = w & 1;
  int m0 = blockIdx.y * 128;
  int n0 = blockIdx.x * 128;

  f32x4 acc[4][4] = {};

  auto stage = [&](int buf, int kt) {
    int k0 = kt * 32;
    #pragma unroll
    for (int r = 0; r < 2; ++r) {
      int c = t + r * 256;
      int row = c >> 2, kc = c & 3;
      gload_lds16(xn  + (size_t)(m0 + row) * D + k0 + kc * 8, &As[buf][c * 8]);
      gload_lds16(wqk + (size_t)(n0 + row) * D + k0 + kc * 8, &Bs[buf][c * 8]);
    }
  };

  stage(0, 0);
  __syncthreads();
  for (int kt = 0; kt < 32; ++kt) {
    int cur = kt & 1;
    if (kt < 31) stage(cur ^ 1, kt + 1);
    short8 a[4], b[4];
    #pragma unroll
    for (int f = 0; f < 4; ++f) {
      int arow = wr * 64 + f * 16 + (lane & 15);
      a[f] = *(const short8*)&As[cur][arow * 32 + (lane >> 4) * 8];
      int brow = wc * 64 + f * 16 + (lane & 15);
      b[f] = *(const short8*)&Bs[cur][brow * 32 + (lane >> 4) * 8];
    }
    #pragma unroll
    for (int i = 0; i < 4; ++i)
      #pragma unroll
      for (int j = 0; j < 4; ++j)
        acc[i][j] = __builtin_amdgcn_mfma_f32_16x16x32_bf16(a[i], b[j], acc[i][j], 0, 0, 0);
    __syncthreads();
  }

  bool isq = (n0 < 1024);
  const float* bias = isq ? bq : bk;
  float scale = isq ? 0.125f : 1.0f;
  unsigned short* outp = isq ? qws : kws;
  int nbase = n0 - (isq ? 0 : 1024);
  #pragma unroll
  for (int i = 0; i < 4; ++i) {
    #pragma unroll
    for (int j = 0; j < 4; ++j) {
      #pragma unroll
      for (int v = 0; v < 4; ++v) {
        int m = m0 + wr * 64 + i * 16 + (lane >> 4) * 4 + v;
        int ncol = nbase + wc * 64 + j * 16 + (lane & 15);
        float val = (acc[i][j][v] + bias[ncol]) * scale;
        int bb = m >> 10, ii = m & 1023;
        int h = ncol >> 6, k = ncol & 63;
        int bh = bb * NHEADS + h;
        size_t off = (size_t)bh * 65536 + (size_t)(ii >> 4) * 1024
                   + (size_t)(k >> 3) * 128 + (ii & 15) * 8 + (k & 7);
        outp[off] = f2bf(val);
      }
    }
  }
}

// ---------------- kernel 5: untied scores + T5 bias -------------------------
// grid (jt=8, it=8, bh=64), 256 thr (4 waves 2x2), 128x128 tile, K=64.
__global__ __launch_bounds__(256) void untied_kernel(const unsigned short* __restrict__ qws,
                                                     const unsigned short* __restrict__ kws,
                                                     const unsigned char* __restrict__ bucket,
                                                     const float* __restrict__ r_emb,
                                                     float* __restrict__ out) {
  __shared__ float rt[33 * 17];
  int t = threadIdx.x;
  for (int idx = t; idx < 528; idx += 256)
    rt[(idx >> 4) * 17 + (idx & 15)] = r_emb[idx];
  __syncthreads();

  int jt = blockIdx.x, it = blockIdx.y, bh = blockIdx.z;
  int b = bh >> 4, h = bh & 15;
  int lane = t & 63, w = t >> 6;
  int wr = w >> 1, wc = w & 1;
  int i0 = it * 128, j0 = jt * 128;

  const unsigned short* qb = qws + (size_t)bh * 65536;
  const unsigned short* kb = kws + (size_t)bh * 65536;

  short8 a[4][2], bf[4][2];
  #pragma unroll
  for (int f = 0; f < 4; ++f) {
    #pragma unroll
    for (int ks = 0; ks < 2; ++ks) {
      a[f][ks]  = *(const short8*)(qb + (size_t)(i0 / 16 + wr * 4 + f) * 1024 + ks * 512 + lane * 8);
      bf[f][ks] = *(const short8*)(kb + (size_t)(j0 / 16 + wc * 4 + f) * 1024 + ks * 512 + lane * 8);
    }
  }

  f32x4 acc[4][4] = {};
  #pragma unroll
  for (int ks = 0; ks < 2; ++ks)
    #pragma unroll
    for (int i = 0; i < 4; ++i)
      #pragma unroll
      for (int j = 0; j < 4; ++j)
        acc[i][j] = __builtin_amdgcn_mfma_f32_16x16x32_bf16(a[i][ks], bf[j][ks], acc[i][j], 0, 0, 0);

  const unsigned char* brow = bucket + (size_t)b * L * L;
  float* ob = out + (size_t)bh * L * L;
  const float* rth = rt + h;
  #pragma unroll
  for (int i = 0; i < 4; ++i) {
    #pragma unroll
    for (int j = 0; j < 4; ++j) {
      #pragma unroll
      for (int v = 0; v < 4; ++v) {
        int ii = i0 + wr * 64 + i * 16 + (lane >> 4) * 4 + v;
        int jj = j0 + wc * 64 + j * 16 + (lane & 15);
        int bk = brow[(size_t)ii * L + jj];
        ob[(size_t)ii * L + jj] = acc[i][j][v] + rth[bk * 17];
      }
    }
  }
}

extern "C" void kernel_launch(void* const* d_in, const int* in_sizes, int n_in,
                              void* d_out, int out_size, void* d_ws, size_t ws_size,
                              hipStream_t stream) {
  const int*   leaf  = (const int*)d_in[0];
  const float* p_emb = (const float*)d_in[1];
  const float* r_emb = (const float*)d_in[2];
  const float* ln_g  = (const float*)d_in[3];
  const float* ln_b  = (const float*)d_in[4];
  const float* Wq    = (const float*)d_in[5];
  const float* bq    = (const float*)d_in[6];
  const float* Wk    = (const float*)d_in[7];
  const float* bk    = (const float*)d_in[8];
  float* out = (float*)d_out;

  char* ws = (char*)d_ws;
  unsigned short* xn   = (unsigned short*)(ws);                        // 8 MiB
  unsigned short* wqk  = (unsigned short*)(ws + (8u  << 20));          // 4 MiB
  unsigned short* qws  = (unsigned short*)(ws + (12u << 20));          // 8 MiB
  unsigned short* kws  = (unsigned short*)(ws + (20u << 20));          // 8 MiB
  unsigned char*  bckt = (unsigned char*)(ws + (28u << 20));           // 4 MiB

  cast_w_kernel<<<2048, 256, 0, stream>>>(Wq, Wk, wqk);
  ln_gather_kernel<<<4096, 256, 0, stream>>>(leaf, p_emb, ln_g, ln_b, xn);
  bucket_kernel<<<16384, 256, 0, stream>>>(leaf, bckt);
  qk_gemm_kernel<<<dim3(16, 32), 256, 0, stream>>>(xn, wqk, bq, bk, qws, kws);
  untied_kernel<<<dim3(8, 8, 64), 256, 0, stream>>>(qws, kws, bckt, r_emb, out);
}

// Round 2
// 110.489 us; speedup vs baseline: 1.0074x; 1.0074x over previous
//
#include <hip/hip_runtime.h>
#include <hip/hip_bf16.h>

typedef __attribute__((ext_vector_type(8))) short short8;
typedef __attribute__((ext_vector_type(4))) float f32x4;

#define L 1024
#define D 1024
#define NHEADS 16

static __device__ __forceinline__ unsigned short f2bf(float f) {
  union { float f; unsigned int u; } c; c.f = f;
  unsigned int u = c.u;
  u += 0x7fffu + ((u >> 16) & 1u);   // round-to-nearest-even
  return (unsigned short)(u >> 16);
}

static __device__ __forceinline__ void gload_lds16(const void* gsrc, void* ldst) {
  __builtin_amdgcn_global_load_lds(
      (const __attribute__((address_space(1))) void*)gsrc,
      (__attribute__((address_space(3))) void*)ldst, 16, 0, 0);
}

// ---------------- kernel 1: merged prep (cast W | gather+LN | bucket) -------
// blocks [0,2048): cast Wq|Wk -> bf16 stacked [2048][1024]
// blocks [2048,6144): gather + LayerNorm -> xn bf16 [4096][1024]
// blocks [6144,22528): T5 bucket u8 [4][1024][1024]
__global__ __launch_bounds__(256) void prep_kernel(const int* __restrict__ leaf,
                                                   const float* __restrict__ p_emb,
                                                   const float* __restrict__ g,
                                                   const float* __restrict__ bcoef,
                                                   const float* __restrict__ Wq,
                                                   const float* __restrict__ Wk,
                                                   unsigned short* __restrict__ w,
                                                   unsigned short* __restrict__ xn,
                                                   unsigned char* __restrict__ bucket) {
  int bid = blockIdx.x;
  int t = threadIdx.x;
  if (bid < 2048) {
    int idx = bid * 256 + t;           // 524288 float4's
    const float* src = (idx < 262144) ? Wq : Wk;
    int rel = (idx < 262144) ? idx : idx - 262144;
    float4 v = ((const float4*)src)[rel];
    ushort4 o;
    o.x = f2bf(v.x); o.y = f2bf(v.y); o.z = f2bf(v.z); o.w = f2bf(v.w);
    ((ushort4*)w)[idx] = o;
  } else if (bid < 6144) {
    int row = bid - 2048;              // 0..4095
    int lane = t & 63, wv = t >> 6;
    int leafv = leaf[row];
    float4 xv = ((const float4*)(p_emb + (size_t)leafv * D))[t];
    float s  = xv.x + xv.y + xv.z + xv.w;
    float s2 = xv.x*xv.x + xv.y*xv.y + xv.z*xv.z + xv.w*xv.w;
    #pragma unroll
    for (int o = 1; o < 64; o <<= 1) {
      s  += __shfl_xor(s, o);
      s2 += __shfl_xor(s2, o);
    }
    __shared__ float red[8];
    if (lane == 0) { red[wv*2] = s; red[wv*2+1] = s2; }
    __syncthreads();
    float st  = red[0] + red[2] + red[4] + red[6];
    float s2t = red[1] + red[3] + red[5] + red[7];
    float mu = st * (1.0f/1024.0f);
    float var = s2t * (1.0f/1024.0f) - mu*mu;
    float rs = rsqrtf(var + 1e-5f);
    float4 gv = ((const float4*)g)[t];
    float4 bv = ((const float4*)bcoef)[t];
    ushort4 o;
    o.x = f2bf((xv.x - mu) * rs * gv.x + bv.x);
    o.y = f2bf((xv.y - mu) * rs * gv.y + bv.y);
    o.z = f2bf((xv.z - mu) * rs * gv.z + bv.z);
    o.w = f2bf((xv.w - mu) * rs * gv.w + bv.w);
    ((ushort4*)xn)[row * 256 + t] = o;
  } else {
    int idx = (bid - 6144) * 256 + t;  // 4M
    int j = idx & 1023;
    int rest = idx >> 10;
    int i = rest & 1023;
    int b = rest >> 10;
    int li = leaf[b * L + i];
    int lj = leaf[b * L + j];
    int n = li - lj;                   // n = -(rel) = leaf[i]-leaf[j]
    int ret = 0;
    if (n < 0) { ret = 16; n = -n; }
    int val;
    if (n < 8) {
      val = n;
    } else {
      val = 8 + (int)(logf((float)n * 0.125f) * 2.8853900817779268f);
      if (val > 15) val = 15;
    }
    val += ret;
    if (li == 0 || lj == 0) val = 32;
    bucket[idx] = (unsigned char)val;
  }
}

// ---------------- kernel 2: fused q/k GEMM (NT, bf16 MFMA) ------------------
// C[m,n] = sum_d xn[m,d]*W'[n,d]; n<1024 -> q (scale 1/8, bias bq), else k.
// Output written in MFMA-fragment-native layout:
//   ws[bh][i>>4][k>>3][i&15][k&7]   (per bh: 64*8*16*8 = 65536 bf16)
// XCD swizzle: each XCD owns 4 consecutive m-panels x all 16 n-tiles.
__global__ __launch_bounds__(256) void qk_gemm_kernel(const unsigned short* __restrict__ xn,
                                                      const unsigned short* __restrict__ wqk,
                                                      const float* __restrict__ bq,
                                                      const float* __restrict__ bk,
                                                      unsigned short* __restrict__ qws,
                                                      unsigned short* __restrict__ kws) {
  __shared__ __align__(16) unsigned short As[2][128 * 32];
  __shared__ __align__(16) unsigned short Bs[2][128 * 32];
  int t = threadIdx.x;
  int lane = t & 63, w = t >> 6;
  int wr = w >> 1, wc = w & 1;
  int wg = blockIdx.x;                     // 0..511
  int swz = (wg & 7) * 64 + (wg >> 3);     // XCD-chunked, bijective (512%8==0)
  int m0 = (swz >> 4) * 128;               // 32 m-tiles
  int n0 = (swz & 15) * 128;               // 16 n-tiles

  f32x4 acc[4][4] = {};

  auto stage = [&](int buf, int kt) {
    int k0 = kt * 32;
    #pragma unroll
    for (int r = 0; r < 2; ++r) {
      int c = t + r * 256;
      int row = c >> 2, kc = c & 3;
      gload_lds16(xn  + (size_t)(m0 + row) * D + k0 + kc * 8, &As[buf][c * 8]);
      gload_lds16(wqk + (size_t)(n0 + row) * D + k0 + kc * 8, &Bs[buf][c * 8]);
    }
  };

  stage(0, 0);
  __syncthreads();
  for (int kt = 0; kt < 32; ++kt) {
    int cur = kt & 1;
    if (kt < 31) stage(cur ^ 1, kt + 1);
    short8 a[4], b[4];
    #pragma unroll
    for (int f = 0; f < 4; ++f) {
      int arow = wr * 64 + f * 16 + (lane & 15);
      a[f] = *(const short8*)&As[cur][arow * 32 + (lane >> 4) * 8];
      int brow = wc * 64 + f * 16 + (lane & 15);
      b[f] = *(const short8*)&Bs[cur][brow * 32 + (lane >> 4) * 8];
    }
    #pragma unroll
    for (int i = 0; i < 4; ++i)
      #pragma unroll
      for (int j = 0; j < 4; ++j)
        acc[i][j] = __builtin_amdgcn_mfma_f32_16x16x32_bf16(a[i], b[j], acc[i][j], 0, 0, 0);
    __syncthreads();
  }

  bool isq = (n0 < 1024);
  const float* bias = isq ? bq : bk;
  float scale = isq ? 0.125f : 1.0f;
  unsigned short* outp = isq ? qws : kws;
  int nbase = n0 - (isq ? 0 : 1024);
  #pragma unroll
  for (int i = 0; i < 4; ++i) {
    #pragma unroll
    for (int j = 0; j < 4; ++j) {
      #pragma unroll
      for (int v = 0; v < 4; ++v) {
        int m = m0 + wr * 64 + i * 16 + (lane >> 4) * 4 + v;
        int ncol = nbase + wc * 64 + j * 16 + (lane & 15);
        float val = (acc[i][j][v] + bias[ncol]) * scale;
        int bb = m >> 10, ii = m & 1023;
        int h = ncol >> 6, k = ncol & 63;
        int bh = bb * NHEADS + h;
        size_t off = (size_t)bh * 65536 + (size_t)(ii >> 4) * 1024
                   + (size_t)(k >> 3) * 128 + (ii & 15) * 8 + (k & 7);
        outp[off] = f2bf(val);
      }
    }
  }
}

// ---------------- kernel 3: untied scores + T5 bias -------------------------
// flat grid 4096, logical id (h fastest): lg = ((b*8+it)*8+jt)*16+h
// XCD-chunked: each XCD gets 512 consecutive logical ids (~4MB working set).
__global__ __launch_bounds__(256) void untied_kernel(const unsigned short* __restrict__ qws,
                                                     const unsigned short* __restrict__ kws,
                                                     const unsigned char* __restrict__ bucket,
                                                     const float* __restrict__ r_emb,
                                                     float* __restrict__ out) {
  __shared__ float rt[33 * 17];
  __shared__ __align__(16) unsigned char bt[128 * 128];
  int t = threadIdx.x;
  for (int idx = t; idx < 528; idx += 256)
    rt[(idx >> 4) * 17 + (idx & 15)] = r_emb[idx];

  int bid = blockIdx.x;
  int lg = (bid & 7) * 512 + (bid >> 3);   // XCD-chunked, bijective (4096%8==0)
  int h  = lg & 15;
  int jt = (lg >> 4) & 7;
  int it = (lg >> 7) & 7;
  int b  = lg >> 10;
  int lane = t & 63, w = t >> 6;
  int wr = w >> 1, wc = w & 1;
  int i0 = it * 128, j0 = jt * 128;
  int bh = b * NHEADS + h;

  // stage bucket tile (16KB) into LDS, XOR-swizzled on the 16B-block index:
  // lds[row*128 + cb*16 + lo] = bucket[i0+row][j0 + ((cb ^ ((row>>2)&3))*16 + lo)]
  const unsigned char* bsrc = bucket + (size_t)b * L * L + (size_t)i0 * L + j0;
  {
    int l = lane;
    #pragma unroll
    for (int iter = 0; iter < 4; ++iter) {
      int lofs = iter * 4096 + w * 1024 + l * 16;  // linear LDS byte offset
      int row = lofs >> 7;
      int cb = (lofs >> 4) & 7;
      int s = (row >> 2) & 3;
      gload_lds16(bsrc + (size_t)row * L + (size_t)((cb ^ s) << 4), &bt[lofs]);
    }
  }

  const unsigned short* qb = qws + (size_t)bh * 65536;
  const unsigned short* kb = kws + (size_t)bh * 65536;

  short8 a[4][2], bf[4][2];
  #pragma unroll
  for (int f = 0; f < 4; ++f) {
    #pragma unroll
    for (int ks = 0; ks < 2; ++ks) {
      a[f][ks]  = *(const short8*)(qb + (size_t)(i0 / 16 + wr * 4 + f) * 1024 + ks * 512 + lane * 8);
      bf[f][ks] = *(const short8*)(kb + (size_t)(j0 / 16 + wc * 4 + f) * 1024 + ks * 512 + lane * 8);
    }
  }

  __syncthreads();   // bucket tile + rt ready (drains vmcnt for global_load_lds)

  f32x4 acc[4][4] = {};
  #pragma unroll
  for (int ks = 0; ks < 2; ++ks)
    #pragma unroll
    for (int i = 0; i < 4; ++i)
      #pragma unroll
      for (int j = 0; j < 4; ++j)
        acc[i][j] = __builtin_amdgcn_mfma_f32_16x16x32_bf16(a[i][ks], bf[j][ks], acc[i][j], 0, 0, 0);

  float* ob = out + (size_t)bh * L * L;
  const float* rth = rt + h;
  #pragma unroll
  for (int i = 0; i < 4; ++i) {
    #pragma unroll
    for (int j = 0; j < 4; ++j) {
      #pragma unroll
      for (int v = 0; v < 4; ++v) {
        int il = wr * 64 + i * 16 + (lane >> 4) * 4 + v;
        int jl = wc * 64 + j * 16 + (lane & 15);
        int bk = bt[il * 128 + (jl ^ (((il >> 2) & 3) << 4))];
        ob[(size_t)(i0 + il) * L + (j0 + jl)] = acc[i][j][v] + rth[bk * 17];
      }
    }
  }
}

extern "C" void kernel_launch(void* const* d_in, const int* in_sizes, int n_in,
                              void* d_out, int out_size, void* d_ws, size_t ws_size,
                              hipStream_t stream) {
  const int*   leaf  = (const int*)d_in[0];
  const float* p_emb = (const float*)d_in[1];
  const float* r_emb = (const float*)d_in[2];
  const float* ln_g  = (const float*)d_in[3];
  const float* ln_b  = (const float*)d_in[4];
  const float* Wq    = (const float*)d_in[5];
  const float* bq    = (const float*)d_in[6];
  const float* Wk    = (const float*)d_in[7];
  const float* bk    = (const float*)d_in[8];
  float* out = (float*)d_out;

  char* ws = (char*)d_ws;
  unsigned short* xn   = (unsigned short*)(ws);                        // 8 MiB
  unsigned short* wqk  = (unsigned short*)(ws + (8u  << 20));          // 4 MiB
  unsigned short* qws  = (unsigned short*)(ws + (12u << 20));          // 8 MiB
  unsigned short* kws  = (unsigned short*)(ws + (20u << 20));          // 8 MiB
  unsigned char*  bckt = (unsigned char*)(ws + (28u << 20));           // 4 MiB

  prep_kernel<<<22528, 256, 0, stream>>>(leaf, p_emb, ln_g, ln_b, Wq, Wk, wqk, xn, bckt);
  qk_gemm_kernel<<<512, 256, 0, stream>>>(xn, wqk, bq, bk, qws, kws);
  untied_kernel<<<4096, 256, 0, stream>>>(qws, kws, bckt, r_emb, out);
}

// Round 3
// 108.891 us; speedup vs baseline: 1.0222x; 1.0147x over previous
//
#include <hip/hip_runtime.h>
#include <hip/hip_bf16.h>

typedef __attribute__((ext_vector_type(8))) short short8;
typedef __attribute__((ext_vector_type(4))) float f32x4;

#define L 1024
#define D 1024
#define NHEADS 16

static __device__ __forceinline__ unsigned short f2bf(float f) {
  union { float f; unsigned int u; } c; c.f = f;
  unsigned int u = c.u;
  u += 0x7fffu + ((u >> 16) & 1u);   // round-to-nearest-even
  return (unsigned short)(u >> 16);
}

static __device__ __forceinline__ void gload_lds16(const void* gsrc, void* ldst) {
  __builtin_amdgcn_global_load_lds(
      (const __attribute__((address_space(1))) void*)gsrc,
      (__attribute__((address_space(3))) void*)ldst, 16, 0, 0);
}

// ---------------- kernel 1: merged prep (cast W | gather+LN | bucket) -------
__global__ __launch_bounds__(256) void prep_kernel(const int* __restrict__ leaf,
                                                   const float* __restrict__ p_emb,
                                                   const float* __restrict__ g,
                                                   const float* __restrict__ bcoef,
                                                   const float* __restrict__ Wq,
                                                   const float* __restrict__ Wk,
                                                   unsigned short* __restrict__ w,
                                                   unsigned short* __restrict__ xn,
                                                   unsigned char* __restrict__ bucket) {
  int bid = blockIdx.x;
  int t = threadIdx.x;
  if (bid < 2048) {
    int idx = bid * 256 + t;           // 524288 float4's
    const float* src = (idx < 262144) ? Wq : Wk;
    int rel = (idx < 262144) ? idx : idx - 262144;
    float4 v = ((const float4*)src)[rel];
    ushort4 o;
    o.x = f2bf(v.x); o.y = f2bf(v.y); o.z = f2bf(v.z); o.w = f2bf(v.w);
    ((ushort4*)w)[idx] = o;
  } else if (bid < 6144) {
    int row = bid - 2048;              // 0..4095
    int lane = t & 63, wv = t >> 6;
    int leafv = leaf[row];
    float4 xv = ((const float4*)(p_emb + (size_t)leafv * D))[t];
    float s  = xv.x + xv.y + xv.z + xv.w;
    float s2 = xv.x*xv.x + xv.y*xv.y + xv.z*xv.z + xv.w*xv.w;
    #pragma unroll
    for (int o = 1; o < 64; o <<= 1) {
      s  += __shfl_xor(s, o);
      s2 += __shfl_xor(s2, o);
    }
    __shared__ float red[8];
    if (lane == 0) { red[wv*2] = s; red[wv*2+1] = s2; }
    __syncthreads();
    float st  = red[0] + red[2] + red[4] + red[6];
    float s2t = red[1] + red[3] + red[5] + red[7];
    float mu = st * (1.0f/1024.0f);
    float var = s2t * (1.0f/1024.0f) - mu*mu;
    float rs = rsqrtf(var + 1e-5f);
    float4 gv = ((const float4*)g)[t];
    float4 bv = ((const float4*)bcoef)[t];
    ushort4 o;
    o.x = f2bf((xv.x - mu) * rs * gv.x + bv.x);
    o.y = f2bf((xv.y - mu) * rs * gv.y + bv.y);
    o.z = f2bf((xv.z - mu) * rs * gv.z + bv.z);
    o.w = f2bf((xv.w - mu) * rs * gv.w + bv.w);
    ((ushort4*)xn)[row * 256 + t] = o;
  } else {
    int idx = (bid - 6144) * 256 + t;  // 4M
    int j = idx & 1023;
    int rest = idx >> 10;
    int i = rest & 1023;
    int b = rest >> 10;
    int li = leaf[b * L + i];
    int lj = leaf[b * L + j];
    int n = li - lj;                   // n = -(rel) = leaf[i]-leaf[j]
    int ret = 0;
    if (n < 0) { ret = 16; n = -n; }
    int val;
    if (n < 8) {
      val = n;
    } else {
      val = 8 + (int)(logf((float)n * 0.125f) * 2.8853900817779268f);
      if (val > 15) val = 15;
    }
    val += ret;
    if (li == 0 || lj == 0) val = 32;
    bucket[idx] = (unsigned char)val;
  }
}

// ---------------- kernel 2: fused q/k GEMM (NT, bf16 MFMA) ------------------
// C[m,n] = sum_d xn[m,d]*W'[n,d]; n<1024 -> q (scale 1/8, bias bq), else k.
// TRANSPOSED mfma (operands swapped): lane holds 4 consecutive n per acc reg
// -> packed 8B stores into fragment-native layout
//   ws[bh][i>>4][k>>3][i&15][k&7]   (per bh: 64*8*16*8 = 65536 bf16)
__global__ __launch_bounds__(256) void qk_gemm_kernel(const unsigned short* __restrict__ xn,
                                                      const unsigned short* __restrict__ wqk,
                                                      const float* __restrict__ bq,
                                                      const float* __restrict__ bk,
                                                      unsigned short* __restrict__ qws,
                                                      unsigned short* __restrict__ kws) {
  __shared__ __align__(16) unsigned short As[2][128 * 32];
  __shared__ __align__(16) unsigned short Bs[2][128 * 32];
  int t = threadIdx.x;
  int lane = t & 63, w = t >> 6;
  int wr = w >> 1, wc = w & 1;
  int wg = blockIdx.x;                     // 0..511
  int swz = (wg & 7) * 64 + (wg >> 3);     // XCD-chunked, bijective (512%8==0)
  int m0 = (swz >> 4) * 128;               // 32 m-tiles
  int n0 = (swz & 15) * 128;               // 16 n-tiles

  f32x4 acc[4][4] = {};

  auto stage = [&](int buf, int kt) {
    int k0 = kt * 32;
    #pragma unroll
    for (int r = 0; r < 2; ++r) {
      int c = t + r * 256;
      int row = c >> 2, kc = c & 3;
      gload_lds16(xn  + (size_t)(m0 + row) * D + k0 + kc * 8, &As[buf][c * 8]);
      gload_lds16(wqk + (size_t)(n0 + row) * D + k0 + kc * 8, &Bs[buf][c * 8]);
    }
  };

  stage(0, 0);
  __syncthreads();
  for (int kt = 0; kt < 32; ++kt) {
    int cur = kt & 1;
    if (kt < 31) stage(cur ^ 1, kt + 1);
    short8 a[4], b[4];
    #pragma unroll
    for (int f = 0; f < 4; ++f) {
      int arow = wr * 64 + f * 16 + (lane & 15);
      a[f] = *(const short8*)&As[cur][arow * 32 + (lane >> 4) * 8];
      int brow = wc * 64 + f * 16 + (lane & 15);
      b[f] = *(const short8*)&Bs[cur][brow * 32 + (lane >> 4) * 8];
    }
    #pragma unroll
    for (int i = 0; i < 4; ++i)
      #pragma unroll
      for (int j = 0; j < 4; ++j)
        acc[i][j] = __builtin_amdgcn_mfma_f32_16x16x32_bf16(b[j], a[i], acc[i][j], 0, 0, 0);
    __syncthreads();
  }

  // acc[i][j]: C rows = n (b's index), cols = m (a's index).
  // lane: m-offset = lane&15 (fixed); n-offset = (lane>>4)*4 + v (4 consecutive n).
  bool isq = (n0 < 1024);
  const float* bias = isq ? bq : bk;
  float scale = isq ? 0.125f : 1.0f;
  unsigned short* outp = isq ? qws : kws;
  int nbase = n0 - (isq ? 0 : 1024);

  float4 bv[4];
  #pragma unroll
  for (int j = 0; j < 4; ++j)
    bv[j] = *(const float4*)(bias + nbase + wc * 64 + j * 16 + (lane >> 4) * 4);

  #pragma unroll
  for (int i = 0; i < 4; ++i) {
    int m = m0 + wr * 64 + i * 16 + (lane & 15);
    int bb = m >> 10, ii = m & 1023;
    #pragma unroll
    for (int j = 0; j < 4; ++j) {
      int n0c = nbase + wc * 64 + j * 16 + (lane >> 4) * 4;   // v=0
      int h = n0c >> 6, k0 = n0c & 63;
      int bh = bb * NHEADS + h;
      float v0 = (acc[i][j][0] + bv[j].x) * scale;
      float v1 = (acc[i][j][1] + bv[j].y) * scale;
      float v2 = (acc[i][j][2] + bv[j].z) * scale;
      float v3 = (acc[i][j][3] + bv[j].w) * scale;
      unsigned p0 = (unsigned)f2bf(v0) | ((unsigned)f2bf(v1) << 16);
      unsigned p1 = (unsigned)f2bf(v2) | ((unsigned)f2bf(v3) << 16);
      size_t off = (size_t)bh * 65536 + (size_t)(ii >> 4) * 1024
                 + (size_t)(k0 >> 3) * 128 + (ii & 15) * 8 + (k0 & 7);
      uint2 pv; pv.x = p0; pv.y = p1;
      *(uint2*)(outp + off) = pv;
    }
  }
}

// ---------------- kernel 3: untied scores + T5 bias -------------------------
// flat grid 4096, logical id (h fastest): lg = ((b*8+it)*8+jt)*16+h
// TRANSPOSED mfma: lane holds 4 consecutive j -> float4 stores + u32 bucket reads.
__global__ __launch_bounds__(256) void untied_kernel(const unsigned short* __restrict__ qws,
                                                     const unsigned short* __restrict__ kws,
                                                     const unsigned char* __restrict__ bucket,
                                                     const float* __restrict__ r_emb,
                                                     float* __restrict__ out) {
  __shared__ float rt[33 * 17];
  __shared__ __align__(16) unsigned char bt[128 * 128];
  int t = threadIdx.x;
  for (int idx = t; idx < 528; idx += 256)
    rt[(idx >> 4) * 17 + (idx & 15)] = r_emb[idx];

  int bid = blockIdx.x;
  int lg = (bid & 7) * 512 + (bid >> 3);   // XCD-chunked, bijective (4096%8==0)
  int h  = lg & 15;
  int jt = (lg >> 4) & 7;
  int it = (lg >> 7) & 7;
  int b  = lg >> 10;
  int lane = t & 63, w = t >> 6;
  int wr = w >> 1, wc = w & 1;
  int i0 = it * 128, j0 = jt * 128;
  int bh = b * NHEADS + h;

  // stage bucket tile (16KB) into LDS, XOR-swizzled on the 16B-block index:
  // LDS block cb of row holds source block (cb ^ (row&7))
  const unsigned char* bsrc = bucket + (size_t)b * L * L + (size_t)i0 * L + j0;
  {
    #pragma unroll
    for (int iter = 0; iter < 4; ++iter) {
      int lofs = iter * 4096 + w * 1024 + lane * 16;  // linear LDS byte offset
      int row = lofs >> 7;
      int cb = (lofs >> 4) & 7;
      gload_lds16(bsrc + (size_t)row * L + (size_t)((cb ^ (row & 7)) << 4), &bt[lofs]);
    }
  }

  const unsigned short* qb = qws + (size_t)bh * 65536;
  const unsigned short* kb = kws + (size_t)bh * 65536;

  short8 a[4][2], bf[4][2];
  #pragma unroll
  for (int f = 0; f < 4; ++f) {
    #pragma unroll
    for (int ks = 0; ks < 2; ++ks) {
      a[f][ks]  = *(const short8*)(qb + (size_t)(i0 / 16 + wr * 4 + f) * 1024 + ks * 512 + lane * 8);
      bf[f][ks] = *(const short8*)(kb + (size_t)(j0 / 16 + wc * 4 + f) * 1024 + ks * 512 + lane * 8);
    }
  }

  __syncthreads();   // bucket tile + rt ready (drains vmcnt for global_load_lds)

  // swapped operands: C rows = j (k's index), cols = i (q's index)
  f32x4 acc[4][4] = {};
  #pragma unroll
  for (int ks = 0; ks < 2; ++ks)
    #pragma unroll
    for (int i = 0; i < 4; ++i)
      #pragma unroll
      for (int j = 0; j < 4; ++j)
        acc[i][j] = __builtin_amdgcn_mfma_f32_16x16x32_bf16(bf[j][ks], a[i][ks], acc[i][j], 0, 0, 0);

  float* ob = out + (size_t)bh * L * L;
  const float* rth = rt + h;
  #pragma unroll
  for (int i = 0; i < 4; ++i) {
    int il = wr * 64 + i * 16 + (lane & 15);          // local i row
    #pragma unroll
    for (int j = 0; j < 4; ++j) {
      int jl = wc * 64 + j * 16 + (lane >> 4) * 4;    // local j (v=0), 4-aligned
      int jd = jl >> 2;                                // dword col 0..31
      int addr = il * 128 + (((jd >> 2) ^ (il & 7)) << 4) + ((jd & 3) << 2);
      unsigned bw = *(const unsigned*)&bt[addr];
      float4 o;
      o.x = acc[i][j][0] + rth[(bw & 255u) * 17];
      o.y = acc[i][j][1] + rth[((bw >> 8) & 255u) * 17];
      o.z = acc[i][j][2] + rth[((bw >> 16) & 255u) * 17];
      o.w = acc[i][j][3] + rth[(bw >> 24) * 17];
      *(float4*)(ob + (size_t)(i0 + il) * L + (j0 + jl)) = o;
    }
  }
}

extern "C" void kernel_launch(void* const* d_in, const int* in_sizes, int n_in,
                              void* d_out, int out_size, void* d_ws, size_t ws_size,
                              hipStream_t stream) {
  const int*   leaf  = (const int*)d_in[0];
  const float* p_emb = (const float*)d_in[1];
  const float* r_emb = (const float*)d_in[2];
  const float* ln_g  = (const float*)d_in[3];
  const float* ln_b  = (const float*)d_in[4];
  const float* Wq    = (const float*)d_in[5];
  const float* bq    = (const float*)d_in[6];
  const float* Wk    = (const float*)d_in[7];
  const float* bk    = (const float*)d_in[8];
  float* out = (float*)d_out;

  char* ws = (char*)d_ws;
  unsigned short* xn   = (unsigned short*)(ws);                        // 8 MiB
  unsigned short* wqk  = (unsigned short*)(ws + (8u  << 20));          // 4 MiB
  unsigned short* qws  = (unsigned short*)(ws + (12u << 20));          // 8 MiB
  unsigned short* kws  = (unsigned short*)(ws + (20u << 20));          // 8 MiB
  unsigned char*  bckt = (unsigned char*)(ws + (28u << 20));           // 4 MiB

  prep_kernel<<<22528, 256, 0, stream>>>(leaf, p_emb, ln_g, ln_b, Wq, Wk, wqk, xn, bckt);
  qk_gemm_kernel<<<512, 256, 0, stream>>>(xn, wqk, bq, bk, qws, kws);
  untied_kernel<<<4096, 256, 0, stream>>>(qws, kws, bckt, r_emb, out);
}

// Round 4
// 105.786 us; speedup vs baseline: 1.0522x; 1.0294x over previous
//
#include <hip/hip_runtime.h>
#include <hip/hip_bf16.h>

typedef __attribute__((ext_vector_type(8))) short short8;
typedef __attribute__((ext_vector_type(4))) float f32x4;

#define L 1024
#define D 1024
#define NHEADS 16

static __device__ __forceinline__ unsigned short f2bf(float f) {
  union { float f; unsigned int u; } c; c.f = f;
  unsigned int u = c.u;
  u += 0x7fffu + ((u >> 16) & 1u);   // round-to-nearest-even
  return (unsigned short)(u >> 16);
}

static __device__ __forceinline__ void gload_lds16(const void* gsrc, void* ldst) {
  __builtin_amdgcn_global_load_lds(
      (const __attribute__((address_space(1))) void*)gsrc,
      (__attribute__((address_space(3))) void*)ldst, 16, 0, 0);
}

// ---------------- kernel 1: merged prep (cast W | gather+LN | bucket) -------
// Wq is pre-scaled by 1/8 during the bf16 cast (exact: power of 2).
__global__ __launch_bounds__(256) void prep_kernel(const int* __restrict__ leaf,
                                                   const float* __restrict__ p_emb,
                                                   const float* __restrict__ g,
                                                   const float* __restrict__ bcoef,
                                                   const float* __restrict__ Wq,
                                                   const float* __restrict__ Wk,
                                                   unsigned short* __restrict__ w,
                                                   unsigned short* __restrict__ xn,
                                                   unsigned char* __restrict__ bucket) {
  int bid = blockIdx.x;
  int t = threadIdx.x;
  if (bid < 2048) {
    int idx = bid * 256 + t;           // 524288 float4's
    bool isq = (idx < 262144);
    const float* src = isq ? Wq : Wk;
    float sc = isq ? 0.125f : 1.0f;
    int rel = isq ? idx : idx - 262144;
    float4 v = ((const float4*)src)[rel];
    ushort4 o;
    o.x = f2bf(v.x * sc); o.y = f2bf(v.y * sc); o.z = f2bf(v.z * sc); o.w = f2bf(v.w * sc);
    ((ushort4*)w)[idx] = o;
  } else if (bid < 6144) {
    int row = bid - 2048;              // 0..4095
    int lane = t & 63, wv = t >> 6;
    int leafv = leaf[row];
    float4 xv = ((const float4*)(p_emb + (size_t)leafv * D))[t];
    float s  = xv.x + xv.y + xv.z + xv.w;
    float s2 = xv.x*xv.x + xv.y*xv.y + xv.z*xv.z + xv.w*xv.w;
    #pragma unroll
    for (int o = 1; o < 64; o <<= 1) {
      s  += __shfl_xor(s, o);
      s2 += __shfl_xor(s2, o);
    }
    __shared__ float red[8];
    if (lane == 0) { red[wv*2] = s; red[wv*2+1] = s2; }
    __syncthreads();
    float st  = red[0] + red[2] + red[4] + red[6];
    float s2t = red[1] + red[3] + red[5] + red[7];
    float mu = st * (1.0f/1024.0f);
    float var = s2t * (1.0f/1024.0f) - mu*mu;
    float rs = rsqrtf(var + 1e-5f);
    float4 gv = ((const float4*)g)[t];
    float4 bv = ((const float4*)bcoef)[t];
    ushort4 o;
    o.x = f2bf((xv.x - mu) * rs * gv.x + bv.x);
    o.y = f2bf((xv.y - mu) * rs * gv.y + bv.y);
    o.z = f2bf((xv.z - mu) * rs * gv.z + bv.z);
    o.w = f2bf((xv.w - mu) * rs * gv.w + bv.w);
    ((ushort4*)xn)[row * 256 + t] = o;
  } else {
    int idx = (bid - 6144) * 256 + t;  // 4M
    int j = idx & 1023;
    int rest = idx >> 10;
    int i = rest & 1023;
    int b = rest >> 10;
    int li = leaf[b * L + i];
    int lj = leaf[b * L + j];
    int n = li - lj;                   // n = -(rel) = leaf[i]-leaf[j]
    int ret = 0;
    if (n < 0) { ret = 16; n = -n; }
    int val;
    if (n < 8) {
      val = n;
    } else {
      val = 8 + (int)(logf((float)n * 0.125f) * 2.8853900817779268f);
      if (val > 15) val = 15;
    }
    val += ret;
    if (li == 0 || lj == 0) val = 32;
    bucket[idx] = (unsigned char)val;
  }
}

// ---------------- kernel 2: fused q/k GEMM (NT, bf16 MFMA) ------------------
// 128x64 tile, 1024 blocks (4 blocks/CU -> 4 independent barrier groups/SIMD).
// C[m,n] = sum_d xn[m,d]*W'[n,d]; n<1024 -> q (Wq pre-scaled), else k.
// TRANSPOSED mfma: lane holds 4 consecutive n per acc reg -> packed 8B stores
// into fragment-native layout ws[bh][i>>4][k>>3][i&15][k&7].
__global__ __launch_bounds__(256) void qk_gemm_kernel(const unsigned short* __restrict__ xn,
                                                      const unsigned short* __restrict__ wqk,
                                                      const float* __restrict__ bq,
                                                      const float* __restrict__ bk,
                                                      unsigned short* __restrict__ qws,
                                                      unsigned short* __restrict__ kws) {
  __shared__ __align__(16) unsigned short As[2][128 * 32];
  __shared__ __align__(16) unsigned short Bs[2][64 * 32];
  int t = threadIdx.x;
  int lane = t & 63, w = t >> 6;
  int wr = w >> 1, wc = w & 1;             // wave tile: 64 m x 32 n
  int wg = blockIdx.x;                     // 0..1023
  int swz = (wg & 7) * 128 + (wg >> 3);    // XCD-chunked, bijective (1024%8==0)
  int m0 = (swz >> 5) * 128;               // 32 m-tiles
  int n0 = (swz & 31) * 64;                // 32 n-tiles

  f32x4 acc[4][2] = {};

  auto stage = [&](int buf, int kt) {
    int k0 = kt * 32;
    #pragma unroll
    for (int r = 0; r < 2; ++r) {
      int c = t + r * 256;
      int row = c >> 2, kc = c & 3;
      gload_lds16(xn + (size_t)(m0 + row) * D + k0 + kc * 8, &As[buf][c * 8]);
    }
    {
      int row = t >> 2, kc = t & 3;
      gload_lds16(wqk + (size_t)(n0 + row) * D + k0 + kc * 8, &Bs[buf][t * 8]);
    }
  };

  stage(0, 0);
  __syncthreads();
  for (int kt = 0; kt < 32; ++kt) {
    int cur = kt & 1;
    if (kt < 31) stage(cur ^ 1, kt + 1);
    short8 a[4], b[2];
    #pragma unroll
    for (int f = 0; f < 4; ++f) {
      int arow = wr * 64 + f * 16 + (lane & 15);
      a[f] = *(const short8*)&As[cur][arow * 32 + (lane >> 4) * 8];
    }
    #pragma unroll
    for (int f = 0; f < 2; ++f) {
      int brow = wc * 32 + f * 16 + (lane & 15);
      b[f] = *(const short8*)&Bs[cur][brow * 32 + (lane >> 4) * 8];
    }
    #pragma unroll
    for (int i = 0; i < 4; ++i)
      #pragma unroll
      for (int j = 0; j < 2; ++j)
        acc[i][j] = __builtin_amdgcn_mfma_f32_16x16x32_bf16(b[j], a[i], acc[i][j], 0, 0, 0);
    __syncthreads();
  }

  // acc[i][j]: C rows = n, cols = m. lane: m-offset = lane&15; n-offset = (lane>>4)*4+v.
  bool isq = (n0 < 1024);
  const float* bias = isq ? bq : bk;
  float scale = isq ? 0.125f : 1.0f;
  unsigned short* outp = isq ? qws : kws;
  int nbase = n0 - (isq ? 0 : 1024);

  float4 bv[2];
  #pragma unroll
  for (int j = 0; j < 2; ++j) {
    bv[j] = *(const float4*)(bias + nbase + wc * 32 + j * 16 + (lane >> 4) * 4);
    bv[j].x *= scale; bv[j].y *= scale; bv[j].z *= scale; bv[j].w *= scale;
  }

  #pragma unroll
  for (int i = 0; i < 4; ++i) {
    int m = m0 + wr * 64 + i * 16 + (lane & 15);
    int bb = m >> 10, ii = m & 1023;
    #pragma unroll
    for (int j = 0; j < 2; ++j) {
      int n0c = nbase + wc * 32 + j * 16 + (lane >> 4) * 4;   // v=0
      int h = n0c >> 6, k0 = n0c & 63;
      int bh = bb * NHEADS + h;
      unsigned p0 = (unsigned)f2bf(acc[i][j][0] + bv[j].x) | ((unsigned)f2bf(acc[i][j][1] + bv[j].y) << 16);
      unsigned p1 = (unsigned)f2bf(acc[i][j][2] + bv[j].z) | ((unsigned)f2bf(acc[i][j][3] + bv[j].w) << 16);
      size_t off = (size_t)bh * 65536 + (size_t)(ii >> 4) * 1024
                 + (size_t)(k0 >> 3) * 128 + (ii & 15) * 8 + (k0 & 7);
      uint2 pv; pv.x = p0; pv.y = p1;
      *(uint2*)(outp + off) = pv;
    }
  }
}

// ---------------- kernel 3: untied scores + T5 bias -------------------------
// flat grid 4096, logical id (h fastest): lg = ((b*8+it)*8+jt)*16+h
// TRANSPOSED mfma: lane holds 4 consecutive j -> float4 stores + u32 bucket reads.
__global__ __launch_bounds__(256) void untied_kernel(const unsigned short* __restrict__ qws,
                                                     const unsigned short* __restrict__ kws,
                                                     const unsigned char* __restrict__ bucket,
                                                     const float* __restrict__ r_emb,
                                                     float* __restrict__ out) {
  __shared__ float rt[33 * 17];
  __shared__ __align__(16) unsigned char bt[128 * 128];
  int t = threadIdx.x;
  for (int idx = t; idx < 528; idx += 256)
    rt[(idx >> 4) * 17 + (idx & 15)] = r_emb[idx];

  int bid = blockIdx.x;
  int lg = (bid & 7) * 512 + (bid >> 3);   // XCD-chunked, bijective (4096%8==0)
  int h  = lg & 15;
  int jt = (lg >> 4) & 7;
  int it = (lg >> 7) & 7;
  int b  = lg >> 10;
  int lane = t & 63, w = t >> 6;
  int wr = w >> 1, wc = w & 1;
  int i0 = it * 128, j0 = jt * 128;
  int bh = b * NHEADS + h;

  // stage bucket tile (16KB) into LDS, XOR-swizzled on the 16B-block index:
  // LDS block cb of row holds source block (cb ^ (row&7))
  const unsigned char* bsrc = bucket + (size_t)b * L * L + (size_t)i0 * L + j0;
  {
    #pragma unroll
    for (int iter = 0; iter < 4; ++iter) {
      int lofs = iter * 4096 + w * 1024 + lane * 16;  // linear LDS byte offset
      int row = lofs >> 7;
      int cb = (lofs >> 4) & 7;
      gload_lds16(bsrc + (size_t)row * L + (size_t)((cb ^ (row & 7)) << 4), &bt[lofs]);
    }
  }

  const unsigned short* qb = qws + (size_t)bh * 65536;
  const unsigned short* kb = kws + (size_t)bh * 65536;

  short8 a[4][2], bf[4][2];
  #pragma unroll
  for (int f = 0; f < 4; ++f) {
    #pragma unroll
    for (int ks = 0; ks < 2; ++ks) {
      a[f][ks]  = *(const short8*)(qb + (size_t)(i0 / 16 + wr * 4 + f) * 1024 + ks * 512 + lane * 8);
      bf[f][ks] = *(const short8*)(kb + (size_t)(j0 / 16 + wc * 4 + f) * 1024 + ks * 512 + lane * 8);
    }
  }

  __syncthreads();   // bucket tile + rt ready (drains vmcnt for global_load_lds)

  // swapped operands: C rows = j (k's index), cols = i (q's index)
  f32x4 acc[4][4] = {};
  #pragma unroll
  for (int ks = 0; ks < 2; ++ks)
    #pragma unroll
    for (int i = 0; i < 4; ++i)
      #pragma unroll
      for (int j = 0; j < 4; ++j)
        acc[i][j] = __builtin_amdgcn_mfma_f32_16x16x32_bf16(bf[j][ks], a[i][ks], acc[i][j], 0, 0, 0);

  // batched bucket-word prefetch (16 independent LDS reads, counted waits)
  unsigned bw[4][4];
  #pragma unroll
  for (int i = 0; i < 4; ++i) {
    int il = wr * 64 + i * 16 + (lane & 15);
    #pragma unroll
    for (int j = 0; j < 4; ++j) {
      int jl = wc * 64 + j * 16 + (lane >> 4) * 4;
      int jd = jl >> 2;
      int addr = il * 128 + (((jd >> 2) ^ (il & 7)) << 4) + ((jd & 3) << 2);
      bw[i][j] = *(const unsigned*)&bt[addr];
    }
  }

  float* ob = out + (size_t)bh * L * L;
  const float* rth = rt + h;
  #pragma unroll
  for (int i = 0; i < 4; ++i) {
    int il = wr * 64 + i * 16 + (lane & 15);          // local i row
    #pragma unroll
    for (int j = 0; j < 4; ++j) {
      int jl = wc * 64 + j * 16 + (lane >> 4) * 4;    // local j (v=0), 4-aligned
      unsigned w32 = bw[i][j];
      float4 o;
      o.x = acc[i][j][0] + rth[(w32 & 255u) * 17];
      o.y = acc[i][j][1] + rth[((w32 >> 8) & 255u) * 17];
      o.z = acc[i][j][2] + rth[((w32 >> 16) & 255u) * 17];
      o.w = acc[i][j][3] + rth[(w32 >> 24) * 17];
      *(float4*)(ob + (size_t)(i0 + il) * L + (j0 + jl)) = o;
    }
  }
}

extern "C" void kernel_launch(void* const* d_in, const int* in_sizes, int n_in,
                              void* d_out, int out_size, void* d_ws, size_t ws_size,
                              hipStream_t stream) {
  const int*   leaf  = (const int*)d_in[0];
  const float* p_emb = (const float*)d_in[1];
  const float* r_emb = (const float*)d_in[2];
  const float* ln_g  = (const float*)d_in[3];
  const float* ln_b  = (const float*)d_in[4];
  const float* Wq    = (const float*)d_in[5];
  const float* bq    = (const float*)d_in[6];
  const float* Wk    = (const float*)d_in[7];
  const float* bk    = (const float*)d_in[8];
  float* out = (float*)d_out;

  char* ws = (char*)d_ws;
  unsigned short* xn   = (unsigned short*)(ws);                        // 8 MiB
  unsigned short* wqk  = (unsigned short*)(ws + (8u  << 20));          // 4 MiB
  unsigned short* qws  = (unsigned short*)(ws + (12u << 20));          // 8 MiB
  unsigned short* kws  = (unsigned short*)(ws + (20u << 20));          // 8 MiB
  unsigned char*  bckt = (unsigned char*)(ws + (28u << 20));           // 4 MiB

  prep_kernel<<<22528, 256, 0, stream>>>(leaf, p_emb, ln_g, ln_b, Wq, Wk, wqk, xn, bckt);
  qk_gemm_kernel<<<1024, 256, 0, stream>>>(xn, wqk, bq, bk, qws, kws);
  untied_kernel<<<4096, 256, 0, stream>>>(qws, kws, bckt, r_emb, out);
}